// Round 17
// baseline (453.442 us; speedup 1.0000x reference)
//
#include <hip/hip_runtime.h>
#include <hip/hip_bf16.h>
#include <cstdint>

// Problem constants (B,S,E,H) = (4, 2048, 256, 8), fp32 in/out.
#define B_N 4
#define S_N 2048
#define E_N 256
#define H_N 8

typedef float f32x4 __attribute__((ext_vector_type(4)));
typedef int i32x4 __attribute__((ext_vector_type(4)));
typedef short s16x8 __attribute__((ext_vector_type(8)));   // 8 bf16 as shorts

static __device__ __forceinline__ f32x4 mfma16(s16x8 a, s16x8 b, f32x4 c) {
  return __builtin_amdgcn_mfma_f32_16x16x32_bf16(a, b, c, 0, 0, 0);
}
static __device__ __forceinline__ i32x4 mfma8i(i32x4 a, i32x4 b, i32x4 c) {
  return __builtin_amdgcn_mfma_i32_16x16x64_i8(a, b, c, 0, 0, 0);
}

// fp32 <-> bf16 (RNE) bit ops.
static __device__ __forceinline__ unsigned short f2bf(float f) {
  union { float f; unsigned int u; } v; v.f = f;
  unsigned int r = v.u + 0x7fffu + ((v.u >> 16) & 1u);
  return (unsigned short)(r >> 16);
}
static __device__ __forceinline__ float bf2f(unsigned short s) {
  union { unsigned int u; float f; } v; v.u = ((unsigned int)s) << 16;
  return v.f;
}
static __device__ __forceinline__ unsigned short f2bf_fast(float f) {
  __hip_bfloat16 h = __float2bfloat16(f);
  return *(unsigned short*)&h;
}

// 15-bit fixed-point limb split: v*scale -> int16 -> (hi8, lo8), exact.
static __device__ __forceinline__ void limbs(float v, float scale, int& hi8, int& lo8) {
  int x = (int)lrintf(v * scale);
  x = x < -32639 ? -32639 : (x > 32639 ? 32639 : x);
  hi8 = (x + 128) >> 8;          // arithmetic shift = floor((x+128)/256)
  lo8 = x - (hi8 << 8);          // in [-128, 127]
}

// Async global->LDS, 16B per lane. LDS dest: wave-uniform base + lane*16.
static __device__ __forceinline__ void gload16(const void* g, void* l) {
  __builtin_amdgcn_global_load_lds(
      (const __attribute__((address_space(1))) unsigned int*)g,
      (__attribute__((address_space(3))) unsigned int*)l, 16, 0, 0);
}

// 16-lane (DPP-row) butterfly reduces — pure VALU, no LDS unit.
static __device__ __forceinline__ float dppmax16(float x) {
  x = fmaxf(x, __int_as_float(__builtin_amdgcn_update_dpp(
          0, __float_as_int(x), 0xB1, 0xF, 0xF, true)));
  x = fmaxf(x, __int_as_float(__builtin_amdgcn_update_dpp(
          0, __float_as_int(x), 0x4E, 0xF, 0xF, true)));
  x = fmaxf(x, __int_as_float(__builtin_amdgcn_update_dpp(
          0, __float_as_int(x), 0x141, 0xF, 0xF, true)));
  x = fmaxf(x, __int_as_float(__builtin_amdgcn_update_dpp(
          0, __float_as_int(x), 0x140, 0xF, 0xF, true)));
  return x;
}
static __device__ __forceinline__ float dppsum16(float x) {
  x = x + __int_as_float(__builtin_amdgcn_update_dpp(
          0, __float_as_int(x), 0xB1, 0xF, 0xF, true));
  x = x + __int_as_float(__builtin_amdgcn_update_dpp(
          0, __float_as_int(x), 0x4E, 0xF, 0xF, true));
  x = x + __int_as_float(__builtin_amdgcn_update_dpp(
          0, __float_as_int(x), 0x141, 0xF, 0xF, true));
  x = x + __int_as_float(__builtin_amdgcn_update_dpp(
          0, __float_as_int(x), 0x140, 0xF, 0xF, true));
  return x;
}

// ---------------------------------------------------------------------------
// Split fp32 -> bf16 hi + bf16 lo.
__global__ void k_split(const float* __restrict__ src, unsigned short* __restrict__ hi,
                        unsigned short* __restrict__ lo, int n4) {
  int i = blockIdx.x * blockDim.x + threadIdx.x;
  if (i >= n4) return;
  float4 v = ((const float4*)src)[i];
  float f[4] = {v.x, v.y, v.z, v.w};
  unsigned short hh[4], ll[4];
#pragma unroll
  for (int j = 0; j < 4; j++) {
    hh[j] = f2bf(f[j]);
    ll[j] = f2bf(f[j] - bf2f(hh[j]));
  }
  ushort4 h; h.x = hh[0]; h.y = hh[1]; h.z = hh[2]; h.w = hh[3];
  ushort4 l; l.x = ll[0]; l.y = ll[1]; l.z = ll[2]; l.w = ll[3];
  ((ushort4*)hi)[i] = h;
  ((ushort4*)lo)[i] = l;
}

// ---------------------------------------------------------------------------
// Split fp32 X -> int8 limbs (scale 4096: X = (256*hi+lo)/4096, bound ~7.97).
__global__ void k_split8(const float* __restrict__ src, signed char* __restrict__ hi,
                         signed char* __restrict__ lo, int n4) {
  int i = blockIdx.x * blockDim.x + threadIdx.x;
  if (i >= n4) return;
  float4 v = ((const float4*)src)[i];
  float f[4] = {v.x, v.y, v.z, v.w};
  signed char hh[4], ll[4];
#pragma unroll
  for (int j = 0; j < 4; j++) {
    int h8, l8;
    limbs(f[j], 4096.f, h8, l8);
    hh[j] = (signed char)h8;
    ll[j] = (signed char)l8;
  }
  *(int*)(hi + i * 4) = *(int*)hh;
  *(int*)(lo + i * 4) = *(int*)ll;
}

// ---------------------------------------------------------------------------
// WvT[h][f][e] = bf16(Wv[h][e][f])
__global__ void k_transpose_wv(const float* __restrict__ wv, unsigned short* __restrict__ wvT) {
  __shared__ float t[32][33];
  int h = blockIdx.z;
  int e0 = blockIdx.x * 32, f0 = blockIdx.y * 32;
  int tx = threadIdx.x & 31, ty = threadIdx.x >> 5;
  const float* src = wv + ((size_t)h * E_N + e0) * E_N + f0;
#pragma unroll
  for (int r = ty; r < 32; r += 8) t[r][tx] = src[(size_t)r * E_N + tx];
  __syncthreads();
  unsigned short* dst = wvT + ((size_t)h * E_N + f0) * E_N + e0;
#pragma unroll
  for (int r = ty; r < 32; r += 8) dst[(size_t)r * E_N + tx] = f2bf(t[tx][r]);
}

// ---------------------------------------------------------------------------
// bt-GEMM: C[m,n] = sum_k A[m,k]*B[n,k], 128x128 tile, BK=32, 4 waves.
// OUT_MODE: 0 = bf16 single, 1 = bf16 hi+lo, 2 = int8 limbs (scale 16).
#define BKP 40  // 32 + 8 pad

template <int TERMS, int OUT_MODE>
__global__ __launch_bounds__(256, 2) void k_gemm(
    const unsigned short* __restrict__ Ahi, const unsigned short* __restrict__ Alo,
    const unsigned short* __restrict__ Bhi, const unsigned short* __restrict__ Blo,
    unsigned short* __restrict__ Chi, unsigned short* __restrict__ Clo,
    int K, int N,
    int aDiv, int aMod, long long aStr,
    int bDiv, int bMod, long long bStr,
    long long cStr) {
  __shared__ unsigned short sA[2][128 * BKP];
  __shared__ unsigned short sB[2][128 * BKP];
  int z = blockIdx.z;
  const unsigned short* A0h = Ahi + (long long)((z / aDiv) % aMod) * aStr;
  const unsigned short* A0l = Alo + (long long)((z / aDiv) % aMod) * aStr;
  const unsigned short* B0h = Bhi + (long long)((z / bDiv) % bMod) * bStr;
  const unsigned short* B0l = Blo + (long long)((z / bDiv) % bMod) * bStr;
  int rT = blockIdx.x * 128, cT = blockIdx.y * 128;
  int tid = threadIdx.x;
  int w = tid >> 6, l = tid & 63, lr = l & 15, lg = l >> 4;
  int wr = w >> 1, wc = w & 1;

  f32x4 acc[4][4];
#pragma unroll
  for (int i = 0; i < 4; i++)
#pragma unroll
    for (int j = 0; j < 4; j++) acc[i][j] = (f32x4){0.f, 0.f, 0.f, 0.f};

  for (int k0 = 0; k0 < K; k0 += 32) {
#pragma unroll
    for (int it = 0; it < 2; it++) {
      int idx = (it * 256 + tid) * 8;
      int r = idx >> 5, c = idx & 31;
      *(s16x8*)&sA[0][r * BKP + c] = *(const s16x8*)(A0h + (size_t)(rT + r) * K + k0 + c);
      *(s16x8*)&sB[0][r * BKP + c] = *(const s16x8*)(B0h + (size_t)(cT + r) * K + k0 + c);
      if (TERMS == 3) {
        *(s16x8*)&sA[1][r * BKP + c] = *(const s16x8*)(A0l + (size_t)(rT + r) * K + k0 + c);
        *(s16x8*)&sB[1][r * BKP + c] = *(const s16x8*)(B0l + (size_t)(cT + r) * K + k0 + c);
      }
    }
    __syncthreads();
    s16x8 ah[4], al[4], bh[4], bl[4];
#pragma unroll
    for (int i = 0; i < 4; i++) {
      ah[i] = *(const s16x8*)&sA[0][(wr * 64 + i * 16 + lr) * BKP + lg * 8];
      if (TERMS == 3) al[i] = *(const s16x8*)&sA[1][(wr * 64 + i * 16 + lr) * BKP + lg * 8];
    }
#pragma unroll
    for (int j = 0; j < 4; j++) {
      bh[j] = *(const s16x8*)&sB[0][(wc * 64 + j * 16 + lr) * BKP + lg * 8];
      if (TERMS == 3) bl[j] = *(const s16x8*)&sB[1][(wc * 64 + j * 16 + lr) * BKP + lg * 8];
    }
#pragma unroll
    for (int i = 0; i < 4; i++)
#pragma unroll
      for (int j = 0; j < 4; j++) {
        acc[i][j] = mfma16(ah[i], bh[j], acc[i][j]);
        if (TERMS == 3) {
          acc[i][j] = mfma16(ah[i], bl[j], acc[i][j]);
          acc[i][j] = mfma16(al[i], bh[j], acc[i][j]);
        }
      }
    __syncthreads();
  }
  long long cOff = (long long)z * cStr;
#pragma unroll
  for (int i = 0; i < 4; i++)
#pragma unroll
    for (int j = 0; j < 4; j++)
#pragma unroll
      for (int r = 0; r < 4; r++) {
        int row = rT + wr * 64 + i * 16 + lg * 4 + r;  // C/D: row=(l>>4)*4+reg
        int col = cT + wc * 64 + j * 16 + lr;          //      col=l&15
        float v = acc[i][j][r];
        long long e = cOff + (size_t)row * N + col;
        if (OUT_MODE == 2) {
          int h8, l8;
          limbs(v, 16.f, h8, l8);   // Y = (256*h8+l8)/16, bound ~2040 (8 sigma)
          ((signed char*)Chi)[e] = (signed char)h8;
          ((signed char*)Clo)[e] = (signed char)l8;
        } else {
          unsigned short hb = f2bf(v);
          Chi[e] = hb;
          if (OUT_MODE == 1) Clo[e] = f2bf(v - bf2f(hb));
        }
      }
}

// ---------------------------------------------------------------------------
// Fused flash attention, round 17: 52 KB LDS -> 3 blocks/CU (12 waves/CU,
// 3 waves/SIMD) to break the latency-bound regime. X single-buffered, VT
// double-buffered; 2 barriers/tile with full latency coverage:
//   vmcnt(0); B1; issue VT[t+1]->other vbuf; S(X[t]); B2; issue X[t+1];
//   softmax; P; PV(vbuf[t&1]).
// VT[t+1] covered by a whole tile body; X[t+1] covered by softmax+P+PV.
// LDS map:
//   0      Xh8 [32 t][256B], slot' = slot ^ (t&15)
//   8192   Xl8 (same swizzle)
//   16384  VT buf0 bf16 [256 f][64B], LINEAR
//   32768  VT buf1
//   49152  P: per wave 1KB [16 q][64B] bf16
#define TT 32
#define ATTN_LDS 53248
#define THR 40.f

__global__ __launch_bounds__(256, 3) void k_attn(
    const signed char* __restrict__ Y8h, const signed char* __restrict__ Y8l,
    const signed char* __restrict__ X8h, const signed char* __restrict__ X8l,
    const unsigned short* __restrict__ VT, float* __restrict__ Out) {
  extern __shared__ char smem[];

  // XCD swizzle, qt-major within bh: 1024 blocks = 8 XCD * 128.
  int obid = blockIdx.x;
  int swz = (obid & 7) * 128 + (obid >> 3);
  int qt = swz & 31, bh = swz >> 5;
  int b = bh >> 3;
  int tid = threadIdx.x, w = tid >> 6, l = tid & 63, lr = l & 15, lg = l >> 4;
  const signed char* Ybh_h = Y8h + (size_t)bh * (S_N * E_N);
  const signed char* Ybh_l = Y8l + (size_t)bh * (S_N * E_N);
  const signed char* Xb_h = X8h + (size_t)b * (S_N * E_N);
  const signed char* Xb_l = X8l + (size_t)b * (S_N * E_N);
  const unsigned short* Vbh = VT + (size_t)bh * (E_N * S_N);
  int qrow = qt * 64 + w * 16;  // 4 waves x 16 q = 64 q-rows per block

  // X-limb staging (inverse swizzle): chunk c=(w*2+i)*64+l, t8=c>>4,
  // stored slot' = c&15 = l&15 holds logical slot = slot' ^ (t8&15).
  int xs8[2];
#pragma unroll
  for (int i = 0; i < 2; i++) {
    int t8 = (w * 2 + i) * 4 + (l >> 4);
    xs8[i] = t8 * 256 + (((l & 15) ^ (t8 & 15)) * 16);  // byte offset in tile
  }
  // VT staging (linear): 4 gloads/wave; chunk c = (w*4+i)*64 + l.
  int vsrc[4];
#pragma unroll
  for (int i = 0; i < 4; i++) {
    int c = (w * 4 + i) * 64 + l;
    vsrc[i] = (c >> 2) * S_N + (c & 3) * 8;             // elements (bf16)
  }

  // X-limb read bases: addr = xrb[kb] + j*4096 (+8192 for lo limb).
  int xrb[4];
#pragma unroll
  for (int kb = 0; kb < 4; kb++)
    xrb[kb] = lr * 256 + (((kb * 4 + lg) ^ lr) * 16);
  int vtbr = lr * 64 + lg * 16;                          // + VB + jf*1024
  int prb = 49152 + w * 1024 + lr * 64 + ((lg * 16) ^ (((lr >> 2) & 3) << 4));
  int pwb = 49152 + w * 1024 + lg * 256;                 // + r*64 + swz byte

  // Hoist Y limb fragments (16 rows x K=256): 4 kb-chunks x 16B per limb.
  i32x4 yh8[4], yl8[4];
#pragma unroll
  for (int kb = 0; kb < 4; kb++) {
    yh8[kb] = *(const i32x4*)(Ybh_h + (size_t)(qrow + lr) * E_N + kb * 64 + lg * 16);
    yl8[kb] = *(const i32x4*)(Ybh_l + (size_t)(qrow + lr) * E_N + kb * 64 + lg * 16);
  }
  f32x4 o[16];
#pragma unroll
  for (int i = 0; i < 16; i++) o[i] = (f32x4){0.f, 0.f, 0.f, 0.f};
  float m2[4], lv[4];
#pragma unroll
  for (int r = 0; r < 4; r++) { m2[r] = -3.0e38f; lv[r] = 0.f; }

  // logit(log2) = S_int * C2T;  C2T = (1/65536)*(1/16)*log2(e)
  const float C2T = 1.3758611398590895e-6f;

  // Prologue: issue X[0] and VT[0] (buf0).
#pragma unroll
  for (int i = 0; i < 2; i++) {
    gload16(Xb_h + xs8[i], smem + (w * 2 + i) * 1024);
    gload16(Xb_l + xs8[i], smem + 8192 + (w * 2 + i) * 1024);
  }
#pragma unroll
  for (int i = 0; i < 4; i++)
    gload16(Vbh + vsrc[i], smem + 16384 + (w * 4 + i) * 1024);

#define TILE_BODY(VB, NVB, t)                                                  \
  {                                                                            \
    asm volatile("s_waitcnt vmcnt(0)" ::: "memory");                           \
    __builtin_amdgcn_s_barrier();                                              \
    if ((t) < 63) {                                                            \
      _Pragma("unroll") for (int i = 0; i < 4; i++)                            \
          gload16(Vbh + ((t) + 1) * TT + vsrc[i],                              \
                  smem + (NVB) + (w * 4 + i) * 1024);                          \
    }                                                                          \
    i32x4 i0[2], i1[2], i2[2];                                                 \
    _Pragma("unroll") for (int j = 0; j < 2; j++) {                            \
      i0[j] = (i32x4){0, 0, 0, 0};                                             \
      i1[j] = (i32x4){0, 0, 0, 0};                                             \
      i2[j] = (i32x4){0, 0, 0, 0};                                             \
    }                                                                          \
    __builtin_amdgcn_s_setprio(1);                                             \
    _Pragma("unroll") for (int j = 0; j < 2; j++) {                            \
      _Pragma("unroll") for (int kb = 0; kb < 4; kb++) {                       \
        i32x4 bh_ = *(const i32x4*)(smem + j * 4096 + xrb[kb]);                \
        i32x4 bl_ = *(const i32x4*)(smem + 8192 + j * 4096 + xrb[kb]);         \
        i0[j] = mfma8i(yh8[kb], bh_, i0[j]);                                   \
        i1[j] = mfma8i(yh8[kb], bl_, i1[j]);                                   \
        i1[j] = mfma8i(yl8[kb], bh_, i1[j]);                                   \
        i2[j] = mfma8i(yl8[kb], bl_, i2[j]);                                   \
      }                                                                        \
    }                                                                          \
    __builtin_amdgcn_s_setprio(0);                                             \
    __builtin_amdgcn_s_barrier();                                              \
    if ((t) < 63) {                                                            \
      _Pragma("unroll") for (int i = 0; i < 2; i++) {                          \
        gload16(Xb_h + (size_t)((t) + 1) * (TT * E_N) + xs8[i],                \
                smem + (w * 2 + i) * 1024);                                    \
        gload16(Xb_l + (size_t)((t) + 1) * (TT * E_N) + xs8[i],                \
                smem + 8192 + (w * 2 + i) * 1024);                             \
      }                                                                        \
    }                                                                          \
    f32x4 sc[2];                                                               \
    _Pragma("unroll") for (int j = 0; j < 2; j++)                              \
        _Pragma("unroll") for (int r = 0; r < 4; r++)                          \
            sc[j][r] = fmaf(65536.f, (float)i0[j][r],                          \
                            fmaf(256.f, (float)i1[j][r], (float)i2[j][r]));    \
    float t2[4];                                                               \
    _Pragma("unroll") for (int r = 0; r < 4; r++)                              \
        t2[r] = fmaxf(sc[0][r], sc[1][r]) * C2T;                               \
    bool ok = (t2[0] <= m2[0] + THR) && (t2[1] <= m2[1] + THR) &&              \
              (t2[2] <= m2[2] + THR) && (t2[3] <= m2[3] + THR);                \
    if (!__all(ok)) {                                                          \
      float fr[4];                                                             \
      _Pragma("unroll") for (int r = 0; r < 4; r++) {                          \
        float rm = dppmax16(t2[r]);                                            \
        float nm = fmaxf(m2[r], rm);                                           \
        fr[r] = exp2f(m2[r] - nm);                                             \
        m2[r] = nm;                                                            \
        lv[r] *= fr[r];                                                        \
      }                                                                        \
      _Pragma("unroll") for (int i = 0; i < 16; i++)                           \
          _Pragma("unroll") for (int r = 0; r < 4; r++) o[i][r] *= fr[r];      \
    }                                                                          \
    float p[2][4];                                                             \
    _Pragma("unroll") for (int j = 0; j < 2; j++)                              \
        _Pragma("unroll") for (int r = 0; r < 4; r++)                          \
            p[j][r] = exp2f(fmaf(sc[j][r], C2T, -m2[r]));                      \
    _Pragma("unroll") for (int r = 0; r < 4; r++) lv[r] += p[0][r] + p[1][r];  \
    _Pragma("unroll") for (int j = 0; j < 2; j++)                              \
        _Pragma("unroll") for (int r = 0; r < 4; r++) {                        \
      int byt = (32 * j + 2 * lr) ^ (lg << 4);                                 \
      *(unsigned short*)(smem + pwb + r * 64 + byt) = f2bf_fast(p[j][r]);      \
    }                                                                          \
    __builtin_amdgcn_s_setprio(1);                                             \
    {                                                                          \
      int vb = (VB) + vtbr;                                                    \
      s16x8 pa = *(const s16x8*)(smem + prb);                                  \
      _Pragma("unroll") for (int jf = 0; jf < 16; jf++) {                      \
        s16x8 bv = *(const s16x8*)(smem + vb + jf * 1024);                     \
        o[jf] = mfma16(pa, bv, o[jf]);                                         \
      }                                                                        \
    }                                                                          \
    __builtin_amdgcn_s_setprio(0);                                             \
  }

  for (int kt = 0; kt < S_N / TT; kt += 2) {
    TILE_BODY(16384, 32768, kt);
    TILE_BODY(32768, 16384, kt + 1);
  }
#undef TILE_BODY

  // Epilogue: finish lv sum-reduce, normalize, head-mean via atomics.
#pragma unroll
  for (int r = 0; r < 4; r++) lv[r] = dppsum16(lv[r]);
#pragma unroll
  for (int jf = 0; jf < 16; jf++)
#pragma unroll
    for (int r = 0; r < 4; r++) {
      float v = o[jf][r] / lv[r] * 0.125f;
      atomicAdd(&Out[((size_t)b * S_N + qrow + lg * 4 + r) * E_N + jf * 16 + lr], v);
    }
}

// ---------------------------------------------------------------------------
extern "C" void kernel_launch(void* const* d_in, const int* in_sizes, int n_in,
                              void* d_out, int out_size, void* d_ws, size_t ws_size,
                              hipStream_t stream) {
  const float* x = (const float*)d_in[0];
  const float* wq = (const float*)d_in[1];
  const float* wk = (const float*)d_in[2];
  const float* wv = (const float*)d_in[3];
  float* out = (float*)d_out;

  // Workspace: bf16 region then int8 region.
  unsigned short* ws = (unsigned short*)d_ws;
  unsigned short* x_hi = ws;                       // [B,S,E] bf16
  unsigned short* x_lo = x_hi + 2097152;
  unsigned short* wq_hi = x_lo + 2097152;          // [H,E,E]
  unsigned short* wq_lo = wq_hi + 524288;
  unsigned short* wk_hi = wq_lo + 524288;
  unsigned short* wk_lo = wk_hi + 524288;
  unsigned short* wvT = wk_lo + 524288;            // [H,E(f),E(e)]
  unsigned short* mt_hi = wvT + 524288;            // [H,E,E] = Wk.Wq^T
  unsigned short* mt_lo = mt_hi + 524288;
  unsigned short* vt = mt_lo + 524288;             // [B,H,E(f),S(t)] bf16
  signed char* i8base = (signed char*)(vt + 16777216);
  signed char* y8h = i8base;                       // [B,H,S,E] int8
  signed char* y8l = y8h + 16777216;
  signed char* x8h = y8l + 16777216;               // [B,S,E] int8
  signed char* x8l = x8h + 2097152;

  hipMemsetAsync(d_out, 0, (size_t)out_size * sizeof(float), stream);

  k_split<<<2048, 256, 0, stream>>>(x, x_hi, x_lo, 524288);
  k_split<<<512, 256, 0, stream>>>(wq, wq_hi, wq_lo, 131072);
  k_split<<<512, 256, 0, stream>>>(wk, wk_hi, wk_lo, 131072);
  k_split8<<<2048, 256, 0, stream>>>(x, x8h, x8l, 524288);
  k_transpose_wv<<<dim3(8, 8, 8), 256, 0, stream>>>(wv, wvT);

  // MT_h = Wk_h . Wq_h^T  (bf16 3-term, bf16 split out)
  k_gemm<3, 1><<<dim3(2, 2, 8), 256, 0, stream>>>(
      wk_hi, wk_lo, wq_hi, wq_lo, mt_hi, mt_lo, 256, 256,
      1, 8, 65536LL, 1, 8, 65536LL, 65536LL);
  // Y[b,h] = X_b . MT_h^T  (bf16 3-term, INT8 limb out)
  k_gemm<3, 2><<<dim3(16, 2, 32), 256, 0, stream>>>(
      x_hi, x_lo, mt_hi, mt_lo, (unsigned short*)y8h, (unsigned short*)y8l,
      256, 256, 8, 4, 524288LL, 1, 8, 65536LL, 524288LL);
  // VT[b,h] = WvT_h . X_b^T  (bf16 single)
  k_gemm<1, 0><<<dim3(2, 16, 32), 256, 0, stream>>>(
      wvT, wvT, x_hi, x_hi, vt, vt, 256, 2048,
      1, 8, 65536LL, 8, 4, 524288LL, 524288LL);

  hipFuncSetAttribute((const void*)k_attn, hipFuncAttributeMaxDynamicSharedMemorySize,
                      ATTN_LDS);
  k_attn<<<dim3(1024), 256, ATTN_LDS, stream>>>(y8h, y8l, x8h, x8l, vt, out);
}

// Round 18
// 341.921 us; speedup vs baseline: 1.3262x; 1.3262x over previous
//
#include <hip/hip_runtime.h>
#include <hip/hip_bf16.h>
#include <cstdint>

// Problem constants (B,S,E,H) = (4, 2048, 256, 8), fp32 in/out.
#define B_N 4
#define S_N 2048
#define E_N 256
#define H_N 8

typedef float f32x4 __attribute__((ext_vector_type(4)));
typedef int i32x4 __attribute__((ext_vector_type(4)));
typedef short s16x8 __attribute__((ext_vector_type(8)));   // 8 bf16 as shorts

static __device__ __forceinline__ f32x4 mfma16(s16x8 a, s16x8 b, f32x4 c) {
  return __builtin_amdgcn_mfma_f32_16x16x32_bf16(a, b, c, 0, 0, 0);
}
static __device__ __forceinline__ i32x4 mfma8i(i32x4 a, i32x4 b, i32x4 c) {
  return __builtin_amdgcn_mfma_i32_16x16x64_i8(a, b, c, 0, 0, 0);
}

// fp32 <-> bf16 (RNE) bit ops.
static __device__ __forceinline__ unsigned short f2bf(float f) {
  union { float f; unsigned int u; } v; v.f = f;
  unsigned int r = v.u + 0x7fffu + ((v.u >> 16) & 1u);
  return (unsigned short)(r >> 16);
}
static __device__ __forceinline__ float bf2f(unsigned short s) {
  union { unsigned int u; float f; } v; v.u = ((unsigned int)s) << 16;
  return v.f;
}
static __device__ __forceinline__ unsigned short f2bf_fast(float f) {
  __hip_bfloat16 h = __float2bfloat16(f);
  return *(unsigned short*)&h;
}

// 15-bit fixed-point limb split: v*scale -> int16 -> (hi8, lo8), exact.
static __device__ __forceinline__ void limbs(float v, float scale, int& hi8, int& lo8) {
  int x = (int)lrintf(v * scale);
  x = x < -32639 ? -32639 : (x > 32639 ? 32639 : x);
  hi8 = (x + 128) >> 8;          // arithmetic shift = floor((x+128)/256)
  lo8 = x - (hi8 << 8);          // in [-128, 127]
}

// Async global->LDS, 16B per lane. LDS dest: wave-uniform base + lane*16.
static __device__ __forceinline__ void gload16(const void* g, void* l) {
  __builtin_amdgcn_global_load_lds(
      (const __attribute__((address_space(1))) unsigned int*)g,
      (__attribute__((address_space(3))) unsigned int*)l, 16, 0, 0);
}

// 16-lane (DPP-row) butterfly reduces — pure VALU, no LDS unit.
static __device__ __forceinline__ float dppmax16(float x) {
  x = fmaxf(x, __int_as_float(__builtin_amdgcn_update_dpp(
          0, __float_as_int(x), 0xB1, 0xF, 0xF, true)));
  x = fmaxf(x, __int_as_float(__builtin_amdgcn_update_dpp(
          0, __float_as_int(x), 0x4E, 0xF, 0xF, true)));
  x = fmaxf(x, __int_as_float(__builtin_amdgcn_update_dpp(
          0, __float_as_int(x), 0x141, 0xF, 0xF, true)));
  x = fmaxf(x, __int_as_float(__builtin_amdgcn_update_dpp(
          0, __float_as_int(x), 0x140, 0xF, 0xF, true)));
  return x;
}
static __device__ __forceinline__ float dppsum16(float x) {
  x = x + __int_as_float(__builtin_amdgcn_update_dpp(
          0, __float_as_int(x), 0xB1, 0xF, 0xF, true));
  x = x + __int_as_float(__builtin_amdgcn_update_dpp(
          0, __float_as_int(x), 0x4E, 0xF, 0xF, true));
  x = x + __int_as_float(__builtin_amdgcn_update_dpp(
          0, __float_as_int(x), 0x141, 0xF, 0xF, true));
  x = x + __int_as_float(__builtin_amdgcn_update_dpp(
          0, __float_as_int(x), 0x140, 0xF, 0xF, true));
  return x;
}

// ---------------------------------------------------------------------------
// Split fp32 -> bf16 hi + bf16 lo.
__global__ void k_split(const float* __restrict__ src, unsigned short* __restrict__ hi,
                        unsigned short* __restrict__ lo, int n4) {
  int i = blockIdx.x * blockDim.x + threadIdx.x;
  if (i >= n4) return;
  float4 v = ((const float4*)src)[i];
  float f[4] = {v.x, v.y, v.z, v.w};
  unsigned short hh[4], ll[4];
#pragma unroll
  for (int j = 0; j < 4; j++) {
    hh[j] = f2bf(f[j]);
    ll[j] = f2bf(f[j] - bf2f(hh[j]));
  }
  ushort4 h; h.x = hh[0]; h.y = hh[1]; h.z = hh[2]; h.w = hh[3];
  ushort4 l; l.x = ll[0]; l.y = ll[1]; l.z = ll[2]; l.w = ll[3];
  ((ushort4*)hi)[i] = h;
  ((ushort4*)lo)[i] = l;
}

// ---------------------------------------------------------------------------
// Split fp32 X -> int8 limbs (scale 4096: X = (256*hi+lo)/4096, bound ~7.97).
__global__ void k_split8(const float* __restrict__ src, signed char* __restrict__ hi,
                         signed char* __restrict__ lo, int n4) {
  int i = blockIdx.x * blockDim.x + threadIdx.x;
  if (i >= n4) return;
  float4 v = ((const float4*)src)[i];
  float f[4] = {v.x, v.y, v.z, v.w};
  signed char hh[4], ll[4];
#pragma unroll
  for (int j = 0; j < 4; j++) {
    int h8, l8;
    limbs(f[j], 4096.f, h8, l8);
    hh[j] = (signed char)h8;
    ll[j] = (signed char)l8;
  }
  *(int*)(hi + i * 4) = *(int*)hh;
  *(int*)(lo + i * 4) = *(int*)ll;
}

// ---------------------------------------------------------------------------
// WvT[h][f][e] = bf16(Wv[h][e][f])
__global__ void k_transpose_wv(const float* __restrict__ wv, unsigned short* __restrict__ wvT) {
  __shared__ float t[32][33];
  int h = blockIdx.z;
  int e0 = blockIdx.x * 32, f0 = blockIdx.y * 32;
  int tx = threadIdx.x & 31, ty = threadIdx.x >> 5;
  const float* src = wv + ((size_t)h * E_N + e0) * E_N + f0;
#pragma unroll
  for (int r = ty; r < 32; r += 8) t[r][tx] = src[(size_t)r * E_N + tx];
  __syncthreads();
  unsigned short* dst = wvT + ((size_t)h * E_N + f0) * E_N + e0;
#pragma unroll
  for (int r = ty; r < 32; r += 8) dst[(size_t)r * E_N + tx] = f2bf(t[tx][r]);
}

// ---------------------------------------------------------------------------
// bt-GEMM: C[m,n] = sum_k A[m,k]*B[n,k], 128x128 tile, BK=32, 4 waves.
// OUT_MODE: 0 = bf16 single, 1 = bf16 hi+lo, 2 = int8 limbs (scale 16).
#define BKP 40  // 32 + 8 pad

template <int TERMS, int OUT_MODE>
__global__ __launch_bounds__(256, 2) void k_gemm(
    const unsigned short* __restrict__ Ahi, const unsigned short* __restrict__ Alo,
    const unsigned short* __restrict__ Bhi, const unsigned short* __restrict__ Blo,
    unsigned short* __restrict__ Chi, unsigned short* __restrict__ Clo,
    int K, int N,
    int aDiv, int aMod, long long aStr,
    int bDiv, int bMod, long long bStr,
    long long cStr) {
  __shared__ unsigned short sA[2][128 * BKP];
  __shared__ unsigned short sB[2][128 * BKP];
  int z = blockIdx.z;
  const unsigned short* A0h = Ahi + (long long)((z / aDiv) % aMod) * aStr;
  const unsigned short* A0l = Alo + (long long)((z / aDiv) % aMod) * aStr;
  const unsigned short* B0h = Bhi + (long long)((z / bDiv) % bMod) * bStr;
  const unsigned short* B0l = Blo + (long long)((z / bDiv) % bMod) * bStr;
  int rT = blockIdx.x * 128, cT = blockIdx.y * 128;
  int tid = threadIdx.x;
  int w = tid >> 6, l = tid & 63, lr = l & 15, lg = l >> 4;
  int wr = w >> 1, wc = w & 1;

  f32x4 acc[4][4];
#pragma unroll
  for (int i = 0; i < 4; i++)
#pragma unroll
    for (int j = 0; j < 4; j++) acc[i][j] = (f32x4){0.f, 0.f, 0.f, 0.f};

  for (int k0 = 0; k0 < K; k0 += 32) {
#pragma unroll
    for (int it = 0; it < 2; it++) {
      int idx = (it * 256 + tid) * 8;
      int r = idx >> 5, c = idx & 31;
      *(s16x8*)&sA[0][r * BKP + c] = *(const s16x8*)(A0h + (size_t)(rT + r) * K + k0 + c);
      *(s16x8*)&sB[0][r * BKP + c] = *(const s16x8*)(B0h + (size_t)(cT + r) * K + k0 + c);
      if (TERMS == 3) {
        *(s16x8*)&sA[1][r * BKP + c] = *(const s16x8*)(A0l + (size_t)(rT + r) * K + k0 + c);
        *(s16x8*)&sB[1][r * BKP + c] = *(const s16x8*)(B0l + (size_t)(cT + r) * K + k0 + c);
      }
    }
    __syncthreads();
    s16x8 ah[4], al[4], bh[4], bl[4];
#pragma unroll
    for (int i = 0; i < 4; i++) {
      ah[i] = *(const s16x8*)&sA[0][(wr * 64 + i * 16 + lr) * BKP + lg * 8];
      if (TERMS == 3) al[i] = *(const s16x8*)&sA[1][(wr * 64 + i * 16 + lr) * BKP + lg * 8];
    }
#pragma unroll
    for (int j = 0; j < 4; j++) {
      bh[j] = *(const s16x8*)&sB[0][(wc * 64 + j * 16 + lr) * BKP + lg * 8];
      if (TERMS == 3) bl[j] = *(const s16x8*)&sB[1][(wc * 64 + j * 16 + lr) * BKP + lg * 8];
    }
#pragma unroll
    for (int i = 0; i < 4; i++)
#pragma unroll
      for (int j = 0; j < 4; j++) {
        acc[i][j] = mfma16(ah[i], bh[j], acc[i][j]);
        if (TERMS == 3) {
          acc[i][j] = mfma16(ah[i], bl[j], acc[i][j]);
          acc[i][j] = mfma16(al[i], bh[j], acc[i][j]);
        }
      }
    __syncthreads();
  }
  long long cOff = (long long)z * cStr;
#pragma unroll
  for (int i = 0; i < 4; i++)
#pragma unroll
    for (int j = 0; j < 4; j++)
#pragma unroll
      for (int r = 0; r < 4; r++) {
        int row = rT + wr * 64 + i * 16 + lg * 4 + r;  // C/D: row=(l>>4)*4+reg
        int col = cT + wc * 64 + j * 16 + lr;          //      col=l&15
        float v = acc[i][j][r];
        long long e = cOff + (size_t)row * N + col;
        if (OUT_MODE == 2) {
          int h8, l8;
          limbs(v, 16.f, h8, l8);   // Y = (256*h8+l8)/16, bound ~2040 (8 sigma)
          ((signed char*)Chi)[e] = (signed char)h8;
          ((signed char*)Clo)[e] = (signed char)l8;
        } else {
          unsigned short hb = f2bf(v);
          Chi[e] = hb;
          if (OUT_MODE == 1) Clo[e] = f2bf(v - bf2f(hb));
        }
      }
}

// ---------------------------------------------------------------------------
// Fused flash attention, round 18: R14/R16 i8-limb scheme at TT=64 (halves
// per-tile fixed costs: 32 barrier/vmcnt crossings instead of 64, half the
// defer-max checks and P bookkeeping). 512 threads, 8 waves x 16 q = 128 q.
// S-phase processes j in pairs {0,1},{2,3} to keep 6 live i32x4 acc chains.
// LDS map, buffer b at base b*65536:
//   +0      Xh8 [64 t][256B], slot' = slot ^ (t&15)  (R14 layout)
//   +16384  Xl8 (same swizzle)
//   +32768  VT bf16 [256 f][128B], byte ^= (row&7)<<4 (R5 layout)
//   131072.. P: per wave 2KB [16 q][128B], write key lg<<4 / read (lr>>2)&3
// Per tile: vmcnt(0) [loads issued one tile ago] -> s_barrier -> issue next
// tile's 8 gloads -> S(i8 limbs, exact i32) -> softmax -> P -> PV(bf16).
#define TT 64
#define BUFS 65536
#define ATTN_LDS 147456
#define THR 40.f

__global__ __launch_bounds__(512, 2) void k_attn(
    const signed char* __restrict__ Y8h, const signed char* __restrict__ Y8l,
    const signed char* __restrict__ X8h, const signed char* __restrict__ X8l,
    const unsigned short* __restrict__ VT, float* __restrict__ Out) {
  extern __shared__ char smem[];

  // XCD swizzle: 512 blocks = 8 XCD * 64; per XCD 4 bh (1 b) x 16 qt.
  int obid = blockIdx.x;
  int swz = (obid & 7) * 64 + (obid >> 3);
  int qt = swz & 15, bh = swz >> 4;
  int b = bh >> 3;
  int tid = threadIdx.x, w = tid >> 6, l = tid & 63, lr = l & 15, lg = l >> 4;
  const signed char* Ybh_h = Y8h + (size_t)bh * (S_N * E_N);
  const signed char* Ybh_l = Y8l + (size_t)bh * (S_N * E_N);
  const signed char* Xb_h = X8h + (size_t)b * (S_N * E_N);
  const signed char* Xb_l = X8l + (size_t)b * (S_N * E_N);
  const unsigned short* Vbh = VT + (size_t)bh * (E_N * S_N);
  int qrow = qt * 128 + w * 16;  // 8 waves x 16 q = 128 q-rows per block

  // X-limb staging (inverse swizzle): chunk c=(w*2+i)*64+l, t8=c>>4 (0..63),
  // stored slot' = c&15 holds logical slot = slot' ^ (t8&15).
  int xs8[2];
#pragma unroll
  for (int i = 0; i < 2; i++) {
    int c = (w * 2 + i) * 64 + l;
    int t8 = c >> 4;
    xs8[i] = t8 * 256 + (((c & 15) ^ (t8 & 15)) * 16);  // byte offset in tile
  }
  // VT staging (inverse swizzle, R5): chunk c=(w*4+i)*64+l, vrow=c>>3 (0..255).
  int vsrc[4];
#pragma unroll
  for (int i = 0; i < 4; i++) {
    int c = (w * 4 + i) * 64 + l;
    int vrow = c >> 3, vbyt = (c & 7) * 16;
    vsrc[i] = vrow * S_N + ((vbyt ^ ((vrow & 7) << 4)) >> 1);  // elements
  }

  // X-limb read bases: addr = CB (+16384 lo) + j*4096 + xrb[kb].
  int xrb[4];
#pragma unroll
  for (int kb = 0; kb < 4; kb++)
    xrb[kb] = lr * 256 + (((kb * 4 + lg) ^ lr) * 16);
  // VT read bases (R5): addr = CB + 32768 + vtb[tc] + jf*2048.
  int vtb[2];
#pragma unroll
  for (int tc = 0; tc < 2; tc++)
    vtb[tc] = lr * 128 + ((tc * 64 + lg * 16) ^ ((lr & 7) << 4));
  // P (R5): per wave 2KB, rows 128B.
  int prb = 131072 + w * 2048 + lr * 128 + ((lg * 16) ^ (((lr >> 2) & 3) << 4));
  int pwb = 131072 + w * 2048 + lg * 512;  // + r*128 + swizzled byte

  // Hoist Y limb fragments (16 rows x K=256): 4 kb-chunks x 16B per limb.
  i32x4 yh8[4], yl8[4];
#pragma unroll
  for (int kb = 0; kb < 4; kb++) {
    yh8[kb] = *(const i32x4*)(Ybh_h + (size_t)(qrow + lr) * E_N + kb * 64 + lg * 16);
    yl8[kb] = *(const i32x4*)(Ybh_l + (size_t)(qrow + lr) * E_N + kb * 64 + lg * 16);
  }
  f32x4 o[16];
#pragma unroll
  for (int i = 0; i < 16; i++) o[i] = (f32x4){0.f, 0.f, 0.f, 0.f};
  float m2[4], lv[4];
#pragma unroll
  for (int r = 0; r < 4; r++) { m2[r] = -3.0e38f; lv[r] = 0.f; }

  // logit(log2) = S_int * C2T;  C2T = (1/65536)*(1/16)*log2(e)
  const float C2T = 1.3758611398590895e-6f;

  // Prologue: issue tile 0 into buf 0.
#pragma unroll
  for (int i = 0; i < 2; i++) {
    gload16(Xb_h + xs8[i], smem + (w * 2 + i) * 1024);
    gload16(Xb_l + xs8[i], smem + 16384 + (w * 2 + i) * 1024);
  }
#pragma unroll
  for (int i = 0; i < 4; i++)
    gload16(Vbh + vsrc[i], smem + 32768 + (w * 4 + i) * 1024);

#define TILE_BODY(CB, NB, t)                                                   \
  {                                                                            \
    asm volatile("s_waitcnt vmcnt(0)" ::: "memory");                           \
    __builtin_amdgcn_s_barrier();                                              \
    if ((t) < 31) {                                                            \
      _Pragma("unroll") for (int i = 0; i < 2; i++) {                          \
        gload16(Xb_h + (size_t)((t) + 1) * (TT * E_N) + xs8[i],                \
                smem + (NB) + (w * 2 + i) * 1024);                             \
        gload16(Xb_l + (size_t)((t) + 1) * (TT * E_N) + xs8[i],                \
                smem + (NB) + 16384 + (w * 2 + i) * 1024);                     \
      }                                                                        \
      _Pragma("unroll") for (int i = 0; i < 4; i++)                            \
          gload16(Vbh + ((t) + 1) * TT + vsrc[i],                              \
                  smem + (NB) + 32768 + (w * 4 + i) * 1024);                   \
    }                                                                          \
    f32x4 sc[4];                                                               \
    __builtin_amdgcn_s_setprio(1);                                             \
    _Pragma("unroll") for (int jp = 0; jp < 4; jp += 2) {                      \
      i32x4 i0[2], i1[2], i2[2];                                               \
      _Pragma("unroll") for (int u = 0; u < 2; u++) {                          \
        i0[u] = (i32x4){0, 0, 0, 0};                                           \
        i1[u] = (i32x4){0, 0, 0, 0};                                           \
        i2[u] = (i32x4){0, 0, 0, 0};                                           \
      }                                                                        \
      _Pragma("unroll") for (int u = 0; u < 2; u++) {                          \
        _Pragma("unroll") for (int kb = 0; kb < 4; kb++) {                     \
          i32x4 bh_ = *(const i32x4*)(smem + (CB) + (jp + u) * 4096 + xrb[kb]);\
          i32x4 bl_ =                                                          \
              *(const i32x4*)(smem + (CB) + 16384 + (jp + u) * 4096 + xrb[kb]);\
          i0[u] = mfma8i(yh8[kb], bh_, i0[u]);                                 \
          i1[u] = mfma8i(yh8[kb], bl_, i1[u]);                                 \
          i1[u] = mfma8i(yl8[kb], bh_, i1[u]);                                 \
          i2[u] = mfma8i(yl8[kb], bl_, i2[u]);                                 \
        }                                                                      \
      }                                                                        \
      _Pragma("unroll") for (int u = 0; u < 2; u++)                            \
          _Pragma("unroll") for (int r = 0; r < 4; r++)                        \
              sc[jp + u][r] = fmaf(65536.f, (float)i0[u][r],                   \
                                   fmaf(256.f, (float)i1[u][r],                \
                                        (float)i2[u][r]));                     \
    }                                                                          \
    __builtin_amdgcn_s_setprio(0);                                             \
    float t2[4];                                                               \
    _Pragma("unroll") for (int r = 0; r < 4; r++)                              \
        t2[r] = fmaxf(fmaxf(sc[0][r], sc[1][r]),                               \
                      fmaxf(sc[2][r], sc[3][r])) * C2T;                        \
    bool ok = (t2[0] <= m2[0] + THR) && (t2[1] <= m2[1] + THR) &&              \
              (t2[2] <= m2[2] + THR) && (t2[3] <= m2[3] + THR);                \
    if (!__all(ok)) {                                                          \
      float fr[4];                                                             \
      _Pragma("unroll") for (int r = 0; r < 4; r++) {                          \
        float rm = dppmax16(t2[r]);                                            \
        float nm = fmaxf(m2[r], rm);                                           \
        fr[r] = exp2f(m2[r] - nm);                                             \
        m2[r] = nm;                                                            \
        lv[r] *= fr[r];                                                        \
      }                                                                        \
      _Pragma("unroll") for (int i = 0; i < 16; i++)                           \
          _Pragma("unroll") for (int r = 0; r < 4; r++) o[i][r] *= fr[r];      \
    }                                                                          \
    float p[4][4];                                                             \
    _Pragma("unroll") for (int j = 0; j < 4; j++)                              \
        _Pragma("unroll") for (int r = 0; r < 4; r++)                          \
            p[j][r] = exp2f(fmaf(sc[j][r], C2T, -m2[r]));                      \
    _Pragma("unroll") for (int r = 0; r < 4; r++)                              \
        lv[r] += (p[0][r] + p[1][r]) + (p[2][r] + p[3][r]);                    \
    _Pragma("unroll") for (int j = 0; j < 4; j++)                              \
        _Pragma("unroll") for (int r = 0; r < 4; r++) {                        \
      int byt = (32 * j + 2 * lr) ^ (lg << 4);                                 \
      *(unsigned short*)(smem + pwb + r * 128 + byt) = f2bf_fast(p[j][r]);     \
    }                                                                          \
    __builtin_amdgcn_s_setprio(1);                                             \
    _Pragma("unroll") for (int tc = 0; tc < 2; tc++) {                         \
      s16x8 pa = *(const s16x8*)(smem + prb + tc * 64);                        \
      _Pragma("unroll") for (int jf = 0; jf < 16; jf++) {                      \
        s16x8 bv =                                                             \
            *(const s16x8*)(smem + (CB) + 32768 + vtb[tc] + jf * 2048);        \
        o[jf] = mfma16(pa, bv, o[jf]);                                         \
      }                                                                        \
    }                                                                          \
    __builtin_amdgcn_s_setprio(0);                                             \
  }

  for (int kt = 0; kt < S_N / TT; kt += 2) {
    TILE_BODY(0, BUFS, kt);
    TILE_BODY(BUFS, 0, kt + 1);
  }
#undef TILE_BODY

  // Epilogue: finish lv sum-reduce, normalize, head-mean via atomics.
#pragma unroll
  for (int r = 0; r < 4; r++) lv[r] = dppsum16(lv[r]);
#pragma unroll
  for (int jf = 0; jf < 16; jf++)
#pragma unroll
    for (int r = 0; r < 4; r++) {
      float v = o[jf][r] / lv[r] * 0.125f;
      atomicAdd(&Out[((size_t)b * S_N + qrow + lg * 4 + r) * E_N + jf * 16 + lr], v);
    }
}

// ---------------------------------------------------------------------------
extern "C" void kernel_launch(void* const* d_in, const int* in_sizes, int n_in,
                              void* d_out, int out_size, void* d_ws, size_t ws_size,
                              hipStream_t stream) {
  const float* x = (const float*)d_in[0];
  const float* wq = (const float*)d_in[1];
  const float* wk = (const float*)d_in[2];
  const float* wv = (const float*)d_in[3];
  float* out = (float*)d_out;

  // Workspace: bf16 region then int8 region.
  unsigned short* ws = (unsigned short*)d_ws;
  unsigned short* x_hi = ws;                       // [B,S,E] bf16
  unsigned short* x_lo = x_hi + 2097152;
  unsigned short* wq_hi = x_lo + 2097152;          // [H,E,E]
  unsigned short* wq_lo = wq_hi + 524288;
  unsigned short* wk_hi = wq_lo + 524288;
  unsigned short* wk_lo = wk_hi + 524288;
  unsigned short* wvT = wk_lo + 524288;            // [H,E(f),E(e)]
  unsigned short* mt_hi = wvT + 524288;            // [H,E,E] = Wk.Wq^T
  unsigned short* mt_lo = mt_hi + 524288;
  unsigned short* vt = mt_lo + 524288;             // [B,H,E(f),S(t)] bf16
  signed char* i8base = (signed char*)(vt + 16777216);
  signed char* y8h = i8base;                       // [B,H,S,E] int8
  signed char* y8l = y8h + 16777216;
  signed char* x8h = y8l + 16777216;               // [B,S,E] int8
  signed char* x8l = x8h + 2097152;

  hipMemsetAsync(d_out, 0, (size_t)out_size * sizeof(float), stream);

  k_split<<<2048, 256, 0, stream>>>(x, x_hi, x_lo, 524288);
  k_split<<<512, 256, 0, stream>>>(wq, wq_hi, wq_lo, 131072);
  k_split<<<512, 256, 0, stream>>>(wk, wk_hi, wk_lo, 131072);
  k_split8<<<2048, 256, 0, stream>>>(x, x8h, x8l, 524288);
  k_transpose_wv<<<dim3(8, 8, 8), 256, 0, stream>>>(wv, wvT);

  // MT_h = Wk_h . Wq_h^T  (bf16 3-term, bf16 split out)
  k_gemm<3, 1><<<dim3(2, 2, 8), 256, 0, stream>>>(
      wk_hi, wk_lo, wq_hi, wq_lo, mt_hi, mt_lo, 256, 256,
      1, 8, 65536LL, 1, 8, 65536LL, 65536LL);
  // Y[b,h] = X_b . MT_h^T  (bf16 3-term, INT8 limb out)
  k_gemm<3, 2><<<dim3(16, 2, 32), 256, 0, stream>>>(
      x_hi, x_lo, mt_hi, mt_lo, (unsigned short*)y8h, (unsigned short*)y8l,
      256, 256, 8, 4, 524288LL, 1, 8, 65536LL, 524288LL);
  // VT[b,h] = WvT_h . X_b^T  (bf16 single)
  k_gemm<1, 0><<<dim3(2, 16, 32), 256, 0, stream>>>(
      wvT, wvT, x_hi, x_hi, vt, vt, 256, 2048,
      1, 8, 65536LL, 8, 4, 524288LL, 524288LL);

  hipFuncSetAttribute((const void*)k_attn, hipFuncAttributeMaxDynamicSharedMemorySize,
                      ATTN_LDS);
  k_attn<<<dim3(512), 512, ATTN_LDS, stream>>>(y8h, y8l, x8h, x8l, vt, out);
}